// Round 1
// baseline (193.506 us; speedup 1.0000x reference)
//
#include <hip/hip_runtime.h>
#include <stdint.h>

// CTC batch cost, forward algorithm. B=512, T=512, C=128 (blank=127), L=64, S=129.
//
// R7: replace per-step scattered HBM gathers (p[lab], p[blank]) with sequential
// streaming of whole rows into LDS via global_load_lds (16B/lane, double-buffered
// 64-row x 512B chunks, counted vmcnt(32) waits — next chunk stays in flight under
// the current chunk's 64 serial steps). Per-step probability reads become
// ds_read_b32 from LDS: p[lab] via an 8-deep register ring (covers ~120cy LDS
// latency), p[blank] via ONE ds_read per chunk (lane r holds row r's blank) +
// compile-time readlane per step. One wave per block -> no barriers at all.
// Recurrence math, rescale cadence and op order are bit-identical to R6.
//
// LINEAR (probability) domain:
//     nA = pl * (aA + upB + skipf*upA)      (label state 2i+1)
//     nB = pb * (aB + aA)                   (blank state 2i+2)
//     aZ *= pb                              (state 0, uniform)
// Cross-lane neighbors via DPP wave_shr:1. Underflow handled by a uniform
// power-of-2 rescale every 8 steps (measure at phase 3, apply stale at phase 7);
// shift folded in with one log2 at the end. lane i owns states 2i+1, 2i+2.

constexpr float EPSF = 1e-7f;
constexpr float LN2F = 0.6931471805599453f;

template<int CTRL>
__device__ __forceinline__ float dpp_mov(float x) {
    return __int_as_float(__builtin_amdgcn_update_dpp(
        0, __float_as_int(x), CTRL, 0xF, 0xF, true));   // bound_ctrl: 0-fill
}

// async global->LDS, 16B per lane; LDS dest = wave-uniform base + lane*16
__device__ __forceinline__ void gload_lds16(const void* g, void* l) {
    __builtin_amdgcn_global_load_lds(
        (const __attribute__((address_space(1))) void*)g,
        (__attribute__((address_space(3))) void*)l, 16, 0, 0);
}

__global__ __launch_bounds__(64)
void ctc_fwd(const int* __restrict__ y_true,
             const float* __restrict__ y_pred,
             float* __restrict__ out)
{
    __shared__ float lds[2][64][128];          // 2 x 32 KB double buffer

    const int b    = blockIdx.x;
    const int lane = threadIdx.x;              // 0..63

    const char* __restrict__ gbase =
        (const char*)(y_pred + (size_t)b * 512 * 128);

    const int   lab   = y_true[b * 64 + lane];     // label of state 2*lane+1
    const int   labp  = __shfl_up(lab, 1, 64);     // prologue-only DS
    const float skipf = (lane > 0 && lab != labp) ? 1.0f : 0.0f;
    const bool  l0    = (lane == 0);

    // ---- stage chunk 0 (rows 0..63) into buffer 0 ----
    {
        const char* g = gbase + lane * 16;
        #pragma unroll
        for (int j = 0; j < 32; ++j)
            gload_lds16(g + j * 1024, (char*)&lds[0][0][0] + j * 1024);
    }

    float aZ = 0.0f, aA = 0.0f, aB = 0.0f;
    int   shift = 0;               // sum of applied log2 scale exponents
    float red   = 0.0f;            // staged wave-max (lane 63 authoritative)

    #pragma unroll 1
    for (int c = 0; c < 8; ++c) {
        // prefetch chunk c+1 into the other buffer, then wait for chunk c only
        if (c < 7) {
            const char* g = gbase + (size_t)(c + 1) * 32768 + lane * 16;
            char*       l = (char*)&lds[(c + 1) & 1][0][0];
            #pragma unroll
            for (int j = 0; j < 32; ++j)
                gload_lds16(g + j * 1024, l + j * 1024);
            // 32 just-issued loads may remain in flight; all older (chunk c) drained
            asm volatile("s_waitcnt vmcnt(32)" ::: "memory");
        } else {
            asm volatile("s_waitcnt vmcnt(0)" ::: "memory");
        }

        const float* ch = &lds[c & 1][0][0];

        // lane r holds row r's blank prob (+EPS), broadcast per-step via readlane
        float vB = ch[lane * 128 + 127] + EPSF;

        // prime 8-deep label-prob ring (rows 0..7 of this chunk)
        float ring[8];
        #pragma unroll
        for (int j = 0; j < 8; ++j) ring[j] = ch[j * 128 + lab];

        #pragma unroll
        for (int u = 0; u < 64; ++u) {
            float pl = ring[u & 7] + EPSF;
            float pb = __int_as_float(
                __builtin_amdgcn_readlane(__float_as_int(vB), u));

            if (c == 0 && u == 0) {
                // t = 0 init: only states 0 and 1 reachable
                aZ = pb;
                aA = l0 ? pl : 0.0f;
                aB = 0.0f;
            } else {
                float upA = dpp_mov<0x138>(aA);    // alpha[2i-1]; lane0 -> 0
                float upB = dpp_mov<0x138>(aB);    // alpha[2i]
                upB = l0 ? aZ : upB;               // lane0's s-1 is state 0
                float ts = aA + upB;
                ts = fmaf(skipf, upA, ts);         // + skip path
                float nA = pl * ts;
                float nB = pb * (aB + aA);
                aZ *= pb;
                aA = nA; aB = nB;
            }

            if ((u & 7) == 3) {                // measure wave-max (applied at +4)
                float r = fmaxf(fmaxf(aA, aB), aZ);
                r = fmaxf(r, dpp_mov<0x111>(r));   // row_shr:1
                r = fmaxf(r, dpp_mov<0x112>(r));   // row_shr:2
                r = fmaxf(r, dpp_mov<0x114>(r));   // row_shr:4
                r = fmaxf(r, dpp_mov<0x118>(r));   // row_shr:8
                r = fmaxf(r, dpp_mov<0x142>(r));   // row_bcast:15
                r = fmaxf(r, dpp_mov<0x143>(r));   // row_bcast:31 -> lane63 = max
                red = r;
            }
            if ((u & 7) == 7) {                // apply uniform 2^k rescale
                int mb = __builtin_amdgcn_readlane(__float_as_int(red), 63);
                int e  = (mb >> 23) & 0xff;
                int f  = 314 - e;              // target: max -> ~2^60
                f = f < 1 ? 1 : (f > 254 ? 254 : f);
                float scale = __int_as_float(f << 23);
                shift += f - 127;
                aA *= scale; aB *= scale; aZ *= scale;
            }

            if (u < 56)                        // refill ring with row u+8
                ring[u & 7] = ch[(u + 8) * 128 + lab];
        }
    }

    // ll = log(alpha[127] + alpha[128]) - shift*ln2; both live on lane 63
    float s   = aA + aB;
    float ll2 = __builtin_amdgcn_logf(s);          // log2
    if (lane == 63) out[b] = ((float)shift - ll2) * LN2F;
}

extern "C" void kernel_launch(void* const* d_in, const int* in_sizes, int n_in,
                              void* d_out, int out_size, void* d_ws, size_t ws_size,
                              hipStream_t stream)
{
    const int*   y_true = (const int*)d_in[0];    // [B, L] int32
    const float* y_pred = (const float*)d_in[1];  // [B, T, C] float32
    float*       out    = (float*)d_out;          // [B, 1] float32

    const int B = out_size;   // 512
    ctc_fwd<<<dim3(B), dim3(64), 0, stream>>>(y_true, y_pred, out);
}

// Round 2
// 193.316 us; speedup vs baseline: 1.0010x; 1.0010x over previous
//
#include <hip/hip_runtime.h>
#include <stdint.h>

// CTC batch cost, forward algorithm. B=512, T=512, C=128 (blank=127), L=64, S=129.
//
// R8 = R7 with a deeper staging pipeline. Evidence from R6/R7 rocprof: the
// timed region is dominated by two 512 MB harness poison-fills (2 x 77 us);
// ctc_fwd itself is ~37 us vs a 21 us HBM floor (134 MB read-once). R7 kept
// only one 32 KB chunk in flight per wave. R8 streams 32-row x 512 B chunks
// (16 KB, 16 x 1 KB global_load_lds) through a 4-buffer LDS ring with THREE
// chunks (48 KB/wave, ~25 MB chip-wide) in flight at all times, and drains
// one chunk at a time with counted s_waitcnt vmcnt(32/16/0) -- never a full
// drain mid-stream. global_load_lds writes no VGPR, so the compiler inserts
// no waits of its own; the asm waits below are the only ordering.
//
// Recurrence (LINEAR probability domain, bit-identical to R6/R7):
//     nA = pl * (aA + upB + skipf*upA)      (label state 2i+1)
//     nB = pb * (aB + aA)                   (blank state 2i+2)
//     aZ *= pb                              (state 0, uniform across lanes)
// Cross-lane neighbors via DPP wave_shr:1. Underflow: uniform power-of-2
// rescale every 8 steps (measure at t%8==3, apply stale at t%8==7); shift
// folded in with one log2 at the end. lane i owns states 2i+1, 2i+2.
// p[lab] via an 8-deep register ring of ds_reads; p[blank] via one ds_read
// per chunk (lane r holds row r's blank) + compile-time readlane per step.
// One wave per block -> no barriers anywhere.

constexpr float EPSF = 1e-7f;
constexpr float LN2F = 0.6931471805599453f;

template<int CTRL>
__device__ __forceinline__ float dpp_mov(float x) {
    return __int_as_float(__builtin_amdgcn_update_dpp(
        0, __float_as_int(x), CTRL, 0xF, 0xF, true));   // bound_ctrl: 0-fill
}

// async global->LDS, 16B per lane; LDS dest = wave-uniform base + lane*16
__device__ __forceinline__ void gload_lds16(const void* g, void* l) {
    __builtin_amdgcn_global_load_lds(
        (const __attribute__((address_space(1))) void*)g,
        (__attribute__((address_space(3))) void*)l, 16, 0, 0);
}

__global__ __launch_bounds__(64)
void ctc_fwd(const int* __restrict__ y_true,
             const float* __restrict__ y_pred,
             float* __restrict__ out)
{
    __shared__ float lds[4][32][128];          // 4 x 16 KB chunk ring (64 KB)

    const int b    = blockIdx.x;
    const int lane = threadIdx.x;              // 0..63

    const char* __restrict__ gbase =
        (const char*)(y_pred + (size_t)b * 512 * 128);

    const int   lab   = y_true[b * 64 + lane];     // label of state 2*lane+1
    const int   labp  = __shfl_up(lab, 1, 64);     // prologue-only DS
    const float skipf = (lane > 0 && lab != labp) ? 1.0f : 0.0f;
    const bool  l0    = (lane == 0);
    const int   rlane = lane & 31;                 // blank-row owner index

    // ---- prologue: issue chunks 0..2 (48 loads in flight) ----
    #pragma unroll
    for (int k = 0; k < 3; ++k) {
        const char* g = gbase + k * 16384 + lane * 16;
        char*       l = (char*)&lds[k][0][0];
        #pragma unroll
        for (int j = 0; j < 16; ++j)
            gload_lds16(g + j * 1024, l + j * 1024);
    }

    float aZ = 0.0f, aA = 0.0f, aB = 0.0f;
    int   shift = 0;               // sum of applied log2 scale exponents
    float red   = 0.0f;            // staged wave-max (lane 63 authoritative)

    #pragma unroll 1
    for (int c = 0; c < 16; ++c) {
        // drain exactly chunk c; keep up to 2 newer chunks in flight
        if (c <= 13)      asm volatile("s_waitcnt vmcnt(32)" ::: "memory");
        else if (c == 14) asm volatile("s_waitcnt vmcnt(16)" ::: "memory");
        else              asm volatile("s_waitcnt vmcnt(0)"  ::: "memory");

        // refill the ring: issue chunk c+3 (outstanding stays <= 48)
        if (c + 3 < 16) {
            const char* g = gbase + (c + 3) * 16384 + lane * 16;
            char*       l = (char*)&lds[(c + 3) & 3][0][0];
            #pragma unroll
            for (int j = 0; j < 16; ++j)
                gload_lds16(g + j * 1024, l + j * 1024);
        }

        const float* ch = &lds[c & 3][0][0];

        // lane r (r<32) holds row r's blank prob (+EPS); broadcast via readlane
        float vB = ch[rlane * 128 + 127] + EPSF;

        // prime 8-deep label-prob ring (rows 0..7 of this chunk)
        float ring[8];
        #pragma unroll
        for (int j = 0; j < 8; ++j) ring[j] = ch[j * 128 + lab] + EPSF;

        const bool first = (c == 0);

        #pragma unroll
        for (int u = 0; u < 32; ++u) {         // t = c*32 + u
            float pl = ring[u & 7];
            float pb = __int_as_float(
                __builtin_amdgcn_readlane(__float_as_int(vB), u));

            if (u == 0 && first) {
                // t = 0 init: only states 0 and 1 reachable
                aZ = pb;
                aA = l0 ? pl : 0.0f;
                aB = 0.0f;
            } else {
                float upA = dpp_mov<0x138>(aA);    // alpha[2i-1]; lane0 -> 0
                float upB = dpp_mov<0x138>(aB);    // alpha[2i]
                upB = l0 ? aZ : upB;               // lane0's s-1 is state 0
                float ts = aA + upB;
                ts = fmaf(skipf, upA, ts);         // + skip path
                float nA = pl * ts;
                float nB = pb * (aB + aA);
                aZ *= pb;
                aA = nA; aB = nB;
            }

            if ((u & 7) == 3) {                // measure wave-max (applied at +4)
                float r = fmaxf(fmaxf(aA, aB), aZ);
                r = fmaxf(r, dpp_mov<0x111>(r));   // row_shr:1
                r = fmaxf(r, dpp_mov<0x112>(r));   // row_shr:2
                r = fmaxf(r, dpp_mov<0x114>(r));   // row_shr:4
                r = fmaxf(r, dpp_mov<0x118>(r));   // row_shr:8
                r = fmaxf(r, dpp_mov<0x142>(r));   // row_bcast:15
                r = fmaxf(r, dpp_mov<0x143>(r));   // row_bcast:31 -> lane63 = max
                red = r;
            }
            if ((u & 7) == 7) {                // apply uniform 2^k rescale
                int mb = __builtin_amdgcn_readlane(__float_as_int(red), 63);
                int e  = (mb >> 23) & 0xff;
                int f  = 314 - e;              // target: max -> ~2^60
                f = f < 1 ? 1 : (f > 254 ? 254 : f);
                float scale = __int_as_float(f << 23);
                shift += f - 127;
                aA *= scale; aB *= scale; aZ *= scale;
            }

            if (u < 24)                        // refill ring with row u+8
                ring[u & 7] = ch[(u + 8) * 128 + lab] + EPSF;
        }
    }

    // ll = log(alpha[127] + alpha[128]) - shift*ln2; both live on lane 63
    float s   = aA + aB;
    float ll2 = __builtin_amdgcn_logf(s);          // log2
    if (lane == 63) out[b] = ((float)shift - ll2) * LN2F;
}

extern "C" void kernel_launch(void* const* d_in, const int* in_sizes, int n_in,
                              void* d_out, int out_size, void* d_ws, size_t ws_size,
                              hipStream_t stream)
{
    const int*   y_true = (const int*)d_in[0];    // [B, L] int32
    const float* y_pred = (const float*)d_in[1];  // [B, T, C] float32
    float*       out    = (float*)d_out;          // [B, 1] float32

    const int B = out_size;   // 512
    ctc_fwd<<<dim3(B), dim3(64), 0, stream>>>(y_true, y_pred, out);
}